// Round 8
// baseline (362.025 us; speedup 1.0000x reference)
//
#include <hip/hip_runtime.h>

#define T_LEN 2048
#define BSZ 4
#define NHEAD 16
#define DHEAD 64
#define DMODEL 1024
#define SCALE 0.125f
#define L2E_SCALE (0.125f * 1.44269504f)   // SCALE*log2(e): folded into Q at projection
#define ROW 72   // padded LDS row stride in bf16 (attn kernel)

typedef __bf16 bf16x8 __attribute__((ext_vector_type(8)));
typedef float f32x4 __attribute__((ext_vector_type(4)));

__device__ __forceinline__ float bf2f(unsigned short u) {
  union { unsigned int i; float f; } v; v.i = ((unsigned int)u) << 16; return v.f;
}
__device__ __forceinline__ unsigned short f2bf(float f) {
  union { float f; unsigned int i; } v; v.f = f;
  unsigned int r = v.i + 0x7fffu + ((v.i >> 16) & 1u);   // RNE
  return (unsigned short)(r >> 16);
}

typedef __attribute__((address_space(1))) void* gptr_t;
typedef __attribute__((address_space(3))) void* lptr_t;

__device__ __forceinline__ void load_lds16(const void* g, void* l) {
  __builtin_amdgcn_global_load_lds((gptr_t)g, (lptr_t)l, 16, 0, 0);
}

// ---- fused fp32->bf16 conversion (blocks 0..12287) + mask prep (block 12288) ----
__global__ __launch_bounds__(256) void cvt_prep(const float* __restrict__ h,
                                                const float* __restrict__ wq,
                                                const float* __restrict__ wkv,
                                                const float* __restrict__ wo,
                                                const unsigned char* __restrict__ mask,
                                                unsigned short* __restrict__ h_bf,
                                                unsigned short* __restrict__ wq_bf,
                                                unsigned short* __restrict__ wkv_bf,
                                                unsigned short* __restrict__ wo_bf,
                                                int* __restrict__ pos,
                                                int* __restrict__ nkeys) {
  const int tid = threadIdx.x;
  if (blockIdx.x < 12288) {
    const size_t E4 = (size_t)T_LEN * BSZ * DMODEL / 4;
    const size_t W4 = (size_t)NHEAD * DHEAD * DMODEL / 4;
    const size_t g = (size_t)blockIdx.x * 256 + tid;
    const float* src; unsigned short* dst; size_t off;
    if (g < E4)                { src = h;   dst = h_bf;   off = g; }
    else if (g < E4 + W4)      { src = wq;  dst = wq_bf;  off = g - E4; }
    else if (g < E4 + 3 * W4)  { src = wkv; dst = wkv_bf; off = g - E4 - W4; }
    else                       { src = wo;  dst = wo_bf;  off = g - E4 - 3 * W4; }
    const float4 v = *(const float4*)(src + off * 4);
    ushort4 o;
    o.x = f2bf(v.x); o.y = f2bf(v.y); o.z = f2bf(v.z); o.w = f2bf(v.w);
    *(ushort4*)(dst + off * 4) = o;
    return;
  }
  __shared__ int s_any;
  if (tid == 0) s_any = 0;
  __syncthreads();
  int acc = 0;
  for (int i = tid; i < T_LEN * BSZ; i += 256)
    if ((i & 3) != 0 && mask[i] != 0) acc = 1;
  if (acc) atomicOr(&s_any, 1);
  __syncthreads();
  const int mmode = s_any ? 0 : 1;   // 1 => int32 layout, 0 => byte layout
  const int wv = tid >> 6, lane = tid & 63;
  const int b = wv;
  int run = 0;
  for (int j0 = 0; j0 < T_LEN; j0 += 64) {
    const int j = j0 + lane;
    const int mval = mmode ? ((const int*)mask)[(size_t)j * BSZ + b]
                           : (int)mask[(size_t)j * BSZ + b];
    const int keep = (mval == 0) ? 1 : 0;
    int x = keep;
#pragma unroll
    for (int off = 1; off < 64; off <<= 1) {
      const int y = __shfl_up(x, off, 64);
      if (lane >= off) x += y;
    }
    pos[b * T_LEN + j] = keep ? (run + x - keep) : -1;
    run += __shfl(x, 63, 64);
  }
  if (lane == 0) nkeys[b] = run;
}

// ---- fused QKV projection: 256x128 tile, BK=64, XOR-swizzled LDS ----
// Q prescaled by L2E_SCALE; K/V^T compacted via pos[].
__global__ __launch_bounds__(256) void gemm_qkv(const unsigned short* __restrict__ A,
                                                const unsigned short* __restrict__ Wq,
                                                const unsigned short* __restrict__ Wkv,
                                                const int* __restrict__ pos,
                                                unsigned short* __restrict__ outQ,
                                                unsigned short* __restrict__ outK,
                                                unsigned short* __restrict__ outVt) {
  __shared__ alignas(16) unsigned short As[256 * 64];   // 32 KB
  __shared__ alignas(16) unsigned short Bs[128 * 64];   // 16 KB
  const int tid  = threadIdx.x;
  const int lane = tid & 63;
  const int wv   = tid >> 6;
  const int m0 = blockIdx.y * 256;
  const int n0 = blockIdx.x * 128;
  const int wrow = (wv >> 1) * 128;
  const int wcol = (wv & 1) * 64;
  const int mi   = lane & 15;
  const int quad = lane >> 4;

  const unsigned short* Abase = A + (size_t)m0 * DMODEL;
  const unsigned short* Bbase = (n0 < DMODEL) ? (Wq + (size_t)n0 * DMODEL)
                                              : (Wkv + (size_t)(n0 - DMODEL) * DMODEL);
  f32x4 acc[8][4] = {};

  // staging maps: A 2048 chunks (8/thread), B 1024 chunks (4/thread), 16B each
  int arow[8], acol[8], brow[4], bcol[4];
#pragma unroll
  for (int c = 0; c < 8; c++) {
    const int s = c * 256 + tid;
    arow[c] = s >> 3; acol[c] = ((s & 7) ^ (arow[c] & 7)) * 8;
  }
#pragma unroll
  for (int c = 0; c < 4; c++) {
    const int s = c * 256 + tid;
    brow[c] = s >> 3; bcol[c] = ((s & 7) ^ (brow[c] & 7)) * 8;
  }
  const int swz = mi & 7;

  for (int k0 = 0; k0 < DMODEL; k0 += 64) {
#pragma unroll
    for (int c = 0; c < 8; c++)
      load_lds16(Abase + (size_t)arow[c] * DMODEL + k0 + acol[c], As + c * 2048 + wv * 512);
#pragma unroll
    for (int c = 0; c < 4; c++)
      load_lds16(Bbase + (size_t)brow[c] * DMODEL + k0 + bcol[c], Bs + c * 2048 + wv * 512);
    __syncthreads();
#pragma unroll
    for (int kq = 0; kq < 2; kq++) {
      const int cp = ((kq * 4 + quad) ^ swz) * 8;
      bf16x8 af[8], bfr[4];
#pragma unroll
      for (int rt = 0; rt < 8; rt++)
        af[rt] = *(const bf16x8*)(As + (wrow + rt * 16 + mi) * 64 + cp);
#pragma unroll
      for (int ct = 0; ct < 4; ct++)
        bfr[ct] = *(const bf16x8*)(Bs + (wcol + ct * 16 + mi) * 64 + cp);
#pragma unroll
      for (int rt = 0; rt < 8; rt++)
#pragma unroll
        for (int ct = 0; ct < 4; ct++)
          acc[rt][ct] = __builtin_amdgcn_mfma_f32_16x16x32_bf16(af[rt], bfr[ct], acc[rt][ct], 0, 0, 0);
    }
    __syncthreads();
  }

  const int region = n0 >> 10;  // uniform per block
#pragma unroll
  for (int rt = 0; rt < 8; rt++) {
#pragma unroll
    for (int r = 0; r < 4; r++) {
      const int gm = m0 + wrow + rt * 16 + quad * 4 + r;
      const int i = gm >> 2, b = gm & 3;
      int p = i;
      if (region > 0) p = pos[b * T_LEN + i];
      if (region > 0 && p < 0) continue;   // masked key: drop
#pragma unroll
      for (int ct = 0; ct < 4; ct++) {
        const int gn = n0 + wcol + ct * 16 + mi;
        const int gnl = gn & (DMODEL - 1);
        const int hn = gnl >> 6, d = gnl & 63;
        const float v = acc[rt][ct][r];
        if (region == 0)
          outQ[(((size_t)b * NHEAD + hn) * T_LEN + i) * DHEAD + d] = f2bf(v * L2E_SCALE);
        else if (region == 1)
          outK[(((size_t)b * NHEAD + hn) * T_LEN + p) * DHEAD + d] = f2bf(v);
        else
          outVt[(((size_t)b * NHEAD + hn) * DHEAD + d) * T_LEN + p] = f2bf(v);
      }
    }
  }
}

// ---- output projection: AV(8192x1024) * wo^T -> bf16 AO; 128x128, BK=64 ----
__global__ __launch_bounds__(256) void gemm_out(const unsigned short* __restrict__ A,
                                                const unsigned short* __restrict__ Bw,
                                                unsigned short* __restrict__ outB) {
  __shared__ alignas(16) unsigned short As[128 * 64];
  __shared__ alignas(16) unsigned short Bs[128 * 64];
  const int tid  = threadIdx.x;
  const int lane = tid & 63;
  const int wv   = tid >> 6;
  const int m0 = blockIdx.y * 128;
  const int n0 = blockIdx.x * 128;
  const int wr = (wv >> 1) * 64;
  const int wc = (wv & 1) * 64;
  const int mi   = lane & 15;
  const int quad = lane >> 4;
  const unsigned short* Abase = A  + (size_t)m0 * DMODEL;
  const unsigned short* Bbase = Bw + (size_t)n0 * DMODEL;

  f32x4 acc[4][4] = {};
  int rowc[4], colc[4];
#pragma unroll
  for (int c = 0; c < 4; c++) {
    const int s = c * 256 + tid;
    rowc[c] = s >> 3;
    colc[c] = ((s & 7) ^ (rowc[c] & 7)) * 8;
  }
  const int swz = mi & 7;
  for (int k0 = 0; k0 < DMODEL; k0 += 64) {
#pragma unroll
    for (int c = 0; c < 4; c++) {
      load_lds16(Abase + (size_t)rowc[c] * DMODEL + k0 + colc[c], As + c * 2048 + wv * 512);
      load_lds16(Bbase + (size_t)rowc[c] * DMODEL + k0 + colc[c], Bs + c * 2048 + wv * 512);
    }
    __syncthreads();
#pragma unroll
    for (int kq = 0; kq < 2; kq++) {
      const int cp = ((kq * 4 + quad) ^ swz) * 8;
      bf16x8 af[4], bfr[4];
#pragma unroll
      for (int rt = 0; rt < 4; rt++)
        af[rt] = *(const bf16x8*)(As + (wr + rt * 16 + mi) * 64 + cp);
#pragma unroll
      for (int ct = 0; ct < 4; ct++)
        bfr[ct] = *(const bf16x8*)(Bs + (wc + ct * 16 + mi) * 64 + cp);
#pragma unroll
      for (int rt = 0; rt < 4; rt++)
#pragma unroll
        for (int ct = 0; ct < 4; ct++)
          acc[rt][ct] = __builtin_amdgcn_mfma_f32_16x16x32_bf16(af[rt], bfr[ct], acc[rt][ct], 0, 0, 0);
    }
    __syncthreads();
  }

#pragma unroll
  for (int rt = 0; rt < 4; rt++)
#pragma unroll
    for (int ct = 0; ct < 4; ct++)
#pragma unroll
      for (int r = 0; r < 4; r++) {
        const int gm = m0 + wr + rt * 16 + quad * 4 + r;
        const int gn = n0 + wc + ct * 16 + mi;
        outB[(size_t)gm * DMODEL + gn] = f2bf(acc[rt][ct][r]);
      }
}

// ---- attention chunk: S^T = K·Q^T (fixed-max exp2), P·V accumulate ----
template<bool TAIL>
__device__ __forceinline__ void attn_chunk(int j0, int nk, int mi, int quad,
    const unsigned short* Ks, const unsigned short* Vts, unsigned short* PsW,
    const bf16x8 (&qb)[2][2], f32x4 (&oc)[2][4], float (&rs)[2]) {
  f32x4 sc[2][4] = {};
#pragma unroll
  for (int ct = 0; ct < 4; ct++) {
    const bf16x8 kf0 = *(const bf16x8*)(Ks + (ct * 16 + mi) * ROW + quad * 8);
    const bf16x8 kf1 = *(const bf16x8*)(Ks + (ct * 16 + mi) * ROW + 32 + quad * 8);
#pragma unroll
    for (int g = 0; g < 2; g++) {
      sc[g][ct] = __builtin_amdgcn_mfma_f32_16x16x32_bf16(kf0, qb[g][0], sc[g][ct], 0, 0, 0);
      sc[g][ct] = __builtin_amdgcn_mfma_f32_16x16x32_bf16(kf1, qb[g][1], sc[g][ct], 0, 0, 0);
    }
  }
#pragma unroll
  for (int g = 0; g < 2; g++)
#pragma unroll
    for (int ct = 0; ct < 4; ct++) {
#pragma unroll
      for (int r = 0; r < 4; r++) {
        float p = __builtin_amdgcn_exp2f(sc[g][ct][r]);
        if (TAIL && (j0 + ct * 16 + quad * 4 + r >= nk)) p = 0.f;
        rs[g] += p;
        sc[g][ct][r] = p;
      }
      union { float f; unsigned u; } c0, c1, c2, c3;
      c0.f = sc[g][ct][0]; c1.f = sc[g][ct][1]; c2.f = sc[g][ct][2]; c3.f = sc[g][ct][3];
      const unsigned pk0 = (c0.u >> 16) | (c1.u & 0xFFFF0000u);   // bf16 trunc pack
      const unsigned pk1 = (c2.u >> 16) | (c3.u & 0xFFFF0000u);
      *(uint2*)(PsW + (g * 16 + mi) * ROW + ct * 16 + quad * 4) = make_uint2(pk0, pk1);
    }
  bf16x8 pa0[2], pa1[2];
#pragma unroll
  for (int g = 0; g < 2; g++) {
    pa0[g] = *(const bf16x8*)(PsW + (g * 16 + mi) * ROW + quad * 8);
    pa1[g] = *(const bf16x8*)(PsW + (g * 16 + mi) * ROW + 32 + quad * 8);
  }
#pragma unroll
  for (int ct = 0; ct < 4; ct++) {
    const bf16x8 vf0 = *(const bf16x8*)(Vts + (ct * 16 + mi) * ROW + quad * 8);
    const bf16x8 vf1 = *(const bf16x8*)(Vts + (ct * 16 + mi) * ROW + 32 + quad * 8);
#pragma unroll
    for (int g = 0; g < 2; g++) {
      oc[g][ct] = __builtin_amdgcn_mfma_f32_16x16x32_bf16(pa0[g], vf0, oc[g][ct], 0, 0, 0);
      oc[g][ct] = __builtin_amdgcn_mfma_f32_16x16x32_bf16(pa1[g], vf1, oc[g][ct], 0, 0, 0);
    }
  }
}

// grid (T/128, B, NH), 256 thr = 4 waves x 32 q-rows (2 groups of 16)
__global__ __launch_bounds__(256, 4) void attn_mfma(const unsigned short* __restrict__ Qg,
                                                    const unsigned short* __restrict__ Kg,
                                                    const unsigned short* __restrict__ Vtg,
                                                    const int* __restrict__ nkeys,
                                                    unsigned short* __restrict__ av) {
  __shared__ alignas(16) unsigned short smem[18688];
  unsigned short* Ks  = smem;
  unsigned short* Vts = smem + 4608;
  unsigned short* Qs  = smem + 9216;
  float* Ls = (float*)(smem + 18432);

  const int tid  = threadIdx.x;
  const int lane = tid & 63;
  const int wv   = tid >> 6;
  const int mi   = lane & 15;
  const int quad = lane >> 4;
  const int i0 = blockIdx.x * 128;
  const int b  = blockIdx.y;
  const int n  = blockIdx.z;
  const size_t base = ((size_t)b * NHEAD + n) * T_LEN * DHEAD;
  const int nk = nkeys[b];

  for (int it = tid; it < 1024; it += 256) {
    const int r = it >> 3, c8 = (it & 7) * 8;
    *(uint4*)(Qs + r * ROW + c8) = *(const uint4*)(Qg + base + (size_t)(i0 + r) * DHEAD + c8);
  }
  __syncthreads();
  bf16x8 qb[2][2];
#pragma unroll
  for (int g = 0; g < 2; g++) {
    qb[g][0] = *(const bf16x8*)(Qs + (wv * 32 + g * 16 + mi) * ROW + quad * 8);
    qb[g][1] = *(const bf16x8*)(Qs + (wv * 32 + g * 16 + mi) * ROW + 32 + quad * 8);
  }

  f32x4 oc[2][4] = {};
  float rs[2] = {0.f, 0.f};
  unsigned short* PsW = Qs + wv * 2304;   // 32*ROW per wave (aliases Qs; safe after barrier)

  const int nmain = nk & ~63;
  for (int j0 = 0; j0 < nmain; j0 += 64) {
    for (int it = tid; it < 512; it += 256) {
      const int r = it >> 3, c8 = (it & 7) * 8;
      *(uint4*)(Ks  + r * ROW + c8) = *(const uint4*)(Kg  + base + (size_t)(j0 + r) * DHEAD + c8);
      *(uint4*)(Vts + r * ROW + c8) = *(const uint4*)(Vtg + base + (size_t)r * T_LEN + j0 + c8);
    }
    __syncthreads();
    attn_chunk<false>(j0, nk, mi, quad, Ks, Vts, PsW, qb, oc, rs);
    __syncthreads();
  }
  if (nmain < nk) {
    for (int it = tid; it < 512; it += 256) {
      const int r = it >> 3, c8 = (it & 7) * 8;
      *(uint4*)(Ks  + r * ROW + c8) = *(const uint4*)(Kg  + base + (size_t)(nmain + r) * DHEAD + c8);
      *(uint4*)(Vts + r * ROW + c8) = *(const uint4*)(Vtg + base + (size_t)r * T_LEN + nmain + c8);
    }
    __syncthreads();
    attn_chunk<true>(nmain, nk, mi, quad, Ks, Vts, PsW, qb, oc, rs);
  }

#pragma unroll
  for (int g = 0; g < 2; g++) {
    float t = rs[g];
    t += __shfl_xor(t, 16, 64);
    t += __shfl_xor(t, 32, 64);
    rs[g] = t;
  }
  if (quad == 0) { Ls[wv * 32 + mi] = rs[0]; Ls[wv * 32 + 16 + mi] = rs[1]; }
  __syncthreads();
  float linv[2][4];
#pragma unroll
  for (int g = 0; g < 2; g++)
#pragma unroll
    for (int r = 0; r < 4; r++) {
      const float l = Ls[wv * 32 + g * 16 + quad * 4 + r];
      linv[g][r] = (l > 0.f) ? (1.f / l) : 0.f;
    }
#pragma unroll
  for (int g = 0; g < 2; g++)
#pragma unroll
    for (int ct = 0; ct < 4; ct++)
#pragma unroll
      for (int r = 0; r < 4; r++) {
        const int q = i0 + wv * 32 + g * 16 + quad * 4 + r;
        const int d = ct * 16 + mi;
        av[((size_t)q * BSZ + b) * DMODEL + n * DHEAD + d] = f2bf(oc[g][ct][r] * linv[g][r]);
      }
}

// ---- out = LayerNorm(h + attn_out)*g + b  (ao bf16, float4 paths) ----
__global__ __launch_bounds__(256) void ln_kernel(const float* __restrict__ h,
                                                 const unsigned short* __restrict__ ao,
                                                 const float* __restrict__ g,
                                                 const float* __restrict__ bb,
                                                 float* __restrict__ out) {
  __shared__ float red[16];
  const int row = blockIdx.x;
  const int tid = threadIdx.x;
  const size_t base = (size_t)row * DMODEL;
  const int c = tid * 4;
  const float4 hv = *(const float4*)(h + base + c);
  const ushort4 a4 = *(const ushort4*)(ao + base + c);
  float x[4] = { hv.x + bf2f(a4.x), hv.y + bf2f(a4.y), hv.z + bf2f(a4.z), hv.w + bf2f(a4.w) };
  float s = 0.f, sq = 0.f;
#pragma unroll
  for (int k = 0; k < 4; k++) { s += x[k]; sq += x[k] * x[k]; }
#pragma unroll
  for (int off = 32; off; off >>= 1) { s += __shfl_xor(s, off, 64); sq += __shfl_xor(sq, off, 64); }
  const int wv = tid >> 6, lane = tid & 63;
  if (lane == 0) { red[wv] = s; red[8 + wv] = sq; }
  __syncthreads();
  if (tid == 0) {
    float ts = 0.f, tq = 0.f;
    for (int w = 0; w < 4; w++) { ts += red[w]; tq += red[8 + w]; }
    red[4] = ts; red[12] = tq;
  }
  __syncthreads();
  const float mu  = red[4] * (1.f / DMODEL);
  const float var = red[12] * (1.f / DMODEL) - mu * mu;
  const float inv = rsqrtf(var + 1e-5f);
  const float4 gv = *(const float4*)(g + c);
  const float4 bv = *(const float4*)(bb + c);
  float4 o;
  o.x = (x[0] - mu) * inv * gv.x + bv.x;
  o.y = (x[1] - mu) * inv * gv.y + bv.y;
  o.z = (x[2] - mu) * inv * gv.z + bv.z;
  o.w = (x[3] - mu) * inv * gv.w + bv.w;
  *(float4*)(out + base + c) = o;
}

extern "C" void kernel_launch(void* const* d_in, const int* in_sizes, int n_in,
                              void* d_out, int out_size, void* d_ws, size_t ws_size,
                              hipStream_t stream) {
  (void)in_sizes; (void)n_in; (void)out_size; (void)ws_size;
  const float* h           = (const float*)d_in[0];
  const unsigned char* msk = (const unsigned char*)d_in[1];
  const float* wq          = (const float*)d_in[2];
  const float* wkv         = (const float*)d_in[3];
  const float* wo          = (const float*)d_in[4];
  const float* lng         = (const float*)d_in[5];
  const float* lnb         = (const float*)d_in[6];
  float* out = (float*)d_out;

  const size_t E  = (size_t)T_LEN * BSZ * DMODEL;        // 8.39M
  const size_t WQ = (size_t)NHEAD * DHEAD * DMODEL;      // 1.05M
  char* ws = (char*)d_ws;
  int* nkeys            = (int*)ws;                       ws += 16;
  int* pos              = (int*)ws;                       ws += (size_t)BSZ * T_LEN * 4;
  unsigned short* h_bf  = (unsigned short*)ws;            ws += E * 2;
  unsigned short* wq_bf = (unsigned short*)ws;            ws += WQ * 2;
  unsigned short* wkv_bf= (unsigned short*)ws;            ws += 2 * WQ * 2;
  unsigned short* wo_bf = (unsigned short*)ws;            ws += WQ * 2;
  unsigned short* Qb    = (unsigned short*)ws;            ws += E * 2;
  unsigned short* Kb    = (unsigned short*)ws;            ws += E * 2;
  unsigned short* Vtb   = (unsigned short*)ws;            ws += E * 2;
  unsigned short* AV    = (unsigned short*)ws;            ws += E * 2;
  unsigned short* AO    = (unsigned short*)ws;

  const dim3 blk(256);
  cvt_prep<<<dim3(12289), blk, 0, stream>>>(h, wq, wkv, wo, msk,
                                            h_bf, wq_bf, wkv_bf, wo_bf, pos, nkeys);
  gemm_qkv<<<dim3(3 * DMODEL / 128, T_LEN * BSZ / 256), blk, 0, stream>>>(
      h_bf, wq_bf, wkv_bf, pos, Qb, Kb, Vtb);
  attn_mfma<<<dim3(T_LEN / 128, BSZ, NHEAD), blk, 0, stream>>>(Qb, Kb, Vtb, nkeys, AV);
  gemm_out<<<dim3(DMODEL / 128, T_LEN * BSZ / 128), blk, 0, stream>>>(AV, wo_bf, AO);
  ln_kernel<<<dim3(T_LEN * BSZ), blk, 0, stream>>>(h, AO, lng, lnb, out);
}

// Round 9
// 313.192 us; speedup vs baseline: 1.1559x; 1.1559x over previous
//
#include <hip/hip_runtime.h>

#define T_LEN 2048
#define BSZ 4
#define NHEAD 16
#define DHEAD 64
#define DMODEL 1024
#define SCALE 0.125f
#define L2E_SCALE (0.125f * 1.44269504f)   // SCALE*log2(e): folded into Q at projection
#define ROW 72   // padded LDS row stride in bf16 (attn kernel)

typedef __bf16 bf16x8 __attribute__((ext_vector_type(8)));
typedef float f32x4 __attribute__((ext_vector_type(4)));

__device__ __forceinline__ float bf2f(unsigned short u) {
  union { unsigned int i; float f; } v; v.i = ((unsigned int)u) << 16; return v.f;
}
__device__ __forceinline__ unsigned short f2bf(float f) {
  union { float f; unsigned int i; } v; v.f = f;
  unsigned int r = v.i + 0x7fffu + ((v.i >> 16) & 1u);   // RNE
  return (unsigned short)(r >> 16);
}

typedef __attribute__((address_space(1))) void* gptr_t;
typedef __attribute__((address_space(3))) void* lptr_t;

__device__ __forceinline__ void load_lds16(const void* g, void* l) {
  __builtin_amdgcn_global_load_lds((gptr_t)g, (lptr_t)l, 16, 0, 0);
}

// ---- fused fp32->bf16 conversion (blocks 0..12287) + mask prep (block 12288) ----
__global__ __launch_bounds__(256) void cvt_prep(const float* __restrict__ h,
                                                const float* __restrict__ wq,
                                                const float* __restrict__ wkv,
                                                const float* __restrict__ wo,
                                                const unsigned char* __restrict__ mask,
                                                unsigned short* __restrict__ h_bf,
                                                unsigned short* __restrict__ wq_bf,
                                                unsigned short* __restrict__ wkv_bf,
                                                unsigned short* __restrict__ wo_bf,
                                                int* __restrict__ pos,
                                                int* __restrict__ nkeys) {
  const int tid = threadIdx.x;
  if (blockIdx.x < 12288) {
    const size_t E4 = (size_t)T_LEN * BSZ * DMODEL / 4;
    const size_t W4 = (size_t)NHEAD * DHEAD * DMODEL / 4;
    const size_t g = (size_t)blockIdx.x * 256 + tid;
    const float* src; unsigned short* dst; size_t off;
    if (g < E4)                { src = h;   dst = h_bf;   off = g; }
    else if (g < E4 + W4)      { src = wq;  dst = wq_bf;  off = g - E4; }
    else if (g < E4 + 3 * W4)  { src = wkv; dst = wkv_bf; off = g - E4 - W4; }
    else                       { src = wo;  dst = wo_bf;  off = g - E4 - 3 * W4; }
    const float4 v = *(const float4*)(src + off * 4);
    ushort4 o;
    o.x = f2bf(v.x); o.y = f2bf(v.y); o.z = f2bf(v.z); o.w = f2bf(v.w);
    *(ushort4*)(dst + off * 4) = o;
    return;
  }
  __shared__ int s_any;
  if (tid == 0) s_any = 0;
  __syncthreads();
  int acc = 0;
  for (int i = tid; i < T_LEN * BSZ; i += 256)
    if ((i & 3) != 0 && mask[i] != 0) acc = 1;
  if (acc) atomicOr(&s_any, 1);
  __syncthreads();
  const int mmode = s_any ? 0 : 1;   // 1 => int32 layout, 0 => byte layout
  const int wv = tid >> 6, lane = tid & 63;
  const int b = wv;
  int run = 0;
  for (int j0 = 0; j0 < T_LEN; j0 += 64) {
    const int j = j0 + lane;
    const int mval = mmode ? ((const int*)mask)[(size_t)j * BSZ + b]
                           : (int)mask[(size_t)j * BSZ + b];
    const int keep = (mval == 0) ? 1 : 0;
    int x = keep;
#pragma unroll
    for (int off = 1; off < 64; off <<= 1) {
      const int y = __shfl_up(x, off, 64);
      if (lane >= off) x += y;
    }
    pos[b * T_LEN + j] = keep ? (run + x - keep) : -1;
    run += __shfl(x, 63, 64);
  }
  if (lane == 0) nkeys[b] = run;
}

// ======== 128x128, BK=64, XOR-swizzled, DOUBLE-BUFFERED GEMM core ========
// Per iter: barrier -> issue loads for k0+64 into other buffer -> compute k0.
// The vmcnt(0) drain at the NEXT barrier waits on loads that overlapped compute.
#define GEMM64_DBUF(Aptr, Bptr)                                                        \
  const int tid  = threadIdx.x;                                                        \
  const int lane = tid & 63;                                                           \
  const int wv   = tid >> 6;                                                           \
  const int wr = (wv >> 1) * 64;                                                       \
  const int wc = (wv & 1) * 64;                                                        \
  const int mi   = lane & 15;                                                          \
  const int quad = lane >> 4;                                                          \
  f32x4 acc[4][4] = {};                                                                \
  int rowc[4], colc[4];                                                                \
  _Pragma("unroll")                                                                    \
  for (int c = 0; c < 4; c++) {                                                        \
    const int s = c * 256 + tid;                                                       \
    rowc[c] = s >> 3;                                                                  \
    colc[c] = ((s & 7) ^ (rowc[c] & 7)) * 8;                                           \
  }                                                                                    \
  const int swz = mi & 7;                                                              \
  _Pragma("unroll")                                                                    \
  for (int c = 0; c < 4; c++) {                                                        \
    load_lds16(Aptr + (size_t)rowc[c] * DMODEL + colc[c], As + c * 2048 + wv * 512);   \
    load_lds16(Bptr + (size_t)rowc[c] * DMODEL + colc[c], Bs + c * 2048 + wv * 512);   \
  }                                                                                    \
  for (int k0 = 0; k0 < DMODEL; k0 += 64) {                                            \
    const int cur = (k0 >> 6) & 1;                                                     \
    const unsigned short* Asr = As + cur * 8192;                                       \
    const unsigned short* Bsr = Bs + cur * 8192;                                       \
    unsigned short* Asw = As + (1 - cur) * 8192;                                       \
    unsigned short* Bsw = Bs + (1 - cur) * 8192;                                       \
    __syncthreads();                                                                   \
    if (k0 + 64 < DMODEL) {                                                            \
      _Pragma("unroll")                                                                \
      for (int c = 0; c < 4; c++) {                                                    \
        load_lds16(Aptr + (size_t)rowc[c] * DMODEL + k0 + 64 + colc[c], Asw + c * 2048 + wv * 512); \
        load_lds16(Bptr + (size_t)rowc[c] * DMODEL + k0 + 64 + colc[c], Bsw + c * 2048 + wv * 512); \
      }                                                                                \
    }                                                                                  \
    _Pragma("unroll")                                                                  \
    for (int kq = 0; kq < 2; kq++) {                                                   \
      const int cp = ((kq * 4 + quad) ^ swz) * 8;                                      \
      bf16x8 af[4], bfr[4];                                                            \
      _Pragma("unroll")                                                                \
      for (int rt = 0; rt < 4; rt++)                                                   \
        af[rt] = *(const bf16x8*)(Asr + (wr + rt * 16 + mi) * 64 + cp);                \
      _Pragma("unroll")                                                                \
      for (int ct = 0; ct < 4; ct++)                                                   \
        bfr[ct] = *(const bf16x8*)(Bsr + (wc + ct * 16 + mi) * 64 + cp);               \
      _Pragma("unroll")                                                                \
      for (int rt = 0; rt < 4; rt++)                                                   \
        _Pragma("unroll")                                                              \
        for (int ct = 0; ct < 4; ct++)                                                 \
          acc[rt][ct] = __builtin_amdgcn_mfma_f32_16x16x32_bf16(af[rt], bfr[ct], acc[rt][ct], 0, 0, 0); \
    }                                                                                  \
  }

// ---- fused QKV projection; Q prescaled by L2E_SCALE; K/V^T compacted ----
__global__ __launch_bounds__(256) void gemm_qkv(const unsigned short* __restrict__ A,
                                                const unsigned short* __restrict__ Wq,
                                                const unsigned short* __restrict__ Wkv,
                                                const int* __restrict__ pos,
                                                unsigned short* __restrict__ outQ,
                                                unsigned short* __restrict__ outK,
                                                unsigned short* __restrict__ outVt) {
  __shared__ alignas(16) unsigned short As[2 * 128 * 64];   // 32 KB
  __shared__ alignas(16) unsigned short Bs[2 * 128 * 64];   // 32 KB
  const int m0 = blockIdx.y * 128;
  const int n0 = blockIdx.x * 128;
  const unsigned short* Abase = A + (size_t)m0 * DMODEL;
  const unsigned short* Bbase = (n0 < DMODEL) ? (Wq + (size_t)n0 * DMODEL)
                                              : (Wkv + (size_t)(n0 - DMODEL) * DMODEL);
  GEMM64_DBUF(Abase, Bbase)

  const int region = n0 >> 10;  // uniform per block
#pragma unroll
  for (int rt = 0; rt < 4; rt++) {
#pragma unroll
    for (int r = 0; r < 4; r++) {
      const int gm = m0 + wr + rt * 16 + quad * 4 + r;
      const int i = gm >> 2, b = gm & 3;
      int p = i;
      if (region > 0) p = pos[b * T_LEN + i];
      if (region > 0 && p < 0) continue;   // masked key: drop
#pragma unroll
      for (int ct = 0; ct < 4; ct++) {
        const int gn = n0 + wc + ct * 16 + mi;
        const int gnl = gn & (DMODEL - 1);
        const int hn = gnl >> 6, d = gnl & 63;
        const float v = acc[rt][ct][r];
        if (region == 0)
          outQ[(((size_t)b * NHEAD + hn) * T_LEN + i) * DHEAD + d] = f2bf(v * L2E_SCALE);
        else if (region == 1)
          outK[(((size_t)b * NHEAD + hn) * T_LEN + p) * DHEAD + d] = f2bf(v);
        else
          outVt[(((size_t)b * NHEAD + hn) * DHEAD + d) * T_LEN + p] = f2bf(v);
      }
    }
  }
}

// ---- output projection: AV(8192x1024) * wo^T -> bf16 AO; 128x128, BK=64 dbuf ----
__global__ __launch_bounds__(256) void gemm_out(const unsigned short* __restrict__ A,
                                                const unsigned short* __restrict__ Bw,
                                                unsigned short* __restrict__ outB) {
  __shared__ alignas(16) unsigned short As[2 * 128 * 64];
  __shared__ alignas(16) unsigned short Bs[2 * 128 * 64];
  const int m0 = blockIdx.y * 128;
  const int n0 = blockIdx.x * 128;
  const unsigned short* Abase = A  + (size_t)m0 * DMODEL;
  const unsigned short* Bbase = Bw + (size_t)n0 * DMODEL;
  GEMM64_DBUF(Abase, Bbase)

#pragma unroll
  for (int rt = 0; rt < 4; rt++)
#pragma unroll
    for (int ct = 0; ct < 4; ct++)
#pragma unroll
      for (int r = 0; r < 4; r++) {
        const int gm = m0 + wr + rt * 16 + quad * 4 + r;
        const int gn = n0 + wc + ct * 16 + mi;
        outB[(size_t)gm * DMODEL + gn] = f2bf(acc[rt][ct][r]);
      }
}

// ---- attention chunk: S^T = K·Q^T (fixed-max exp2), P·V accumulate ----
template<bool TAIL>
__device__ __forceinline__ void attn_chunk(int j0, int nk, int mi, int quad,
    const unsigned short* Ks, const unsigned short* Vts, unsigned short* PsW,
    const bf16x8 (&qb)[2][2], f32x4 (&oc)[2][4], float (&rs)[2]) {
  f32x4 sc[2][4] = {};
#pragma unroll
  for (int ct = 0; ct < 4; ct++) {
    const bf16x8 kf0 = *(const bf16x8*)(Ks + (ct * 16 + mi) * ROW + quad * 8);
    const bf16x8 kf1 = *(const bf16x8*)(Ks + (ct * 16 + mi) * ROW + 32 + quad * 8);
#pragma unroll
    for (int g = 0; g < 2; g++) {
      sc[g][ct] = __builtin_amdgcn_mfma_f32_16x16x32_bf16(kf0, qb[g][0], sc[g][ct], 0, 0, 0);
      sc[g][ct] = __builtin_amdgcn_mfma_f32_16x16x32_bf16(kf1, qb[g][1], sc[g][ct], 0, 0, 0);
    }
  }
#pragma unroll
  for (int g = 0; g < 2; g++)
#pragma unroll
    for (int ct = 0; ct < 4; ct++) {
#pragma unroll
      for (int r = 0; r < 4; r++) {
        float p = __builtin_amdgcn_exp2f(sc[g][ct][r]);
        if (TAIL && (j0 + ct * 16 + quad * 4 + r >= nk)) p = 0.f;
        rs[g] += p;
        sc[g][ct][r] = p;
      }
      union { float f; unsigned u; } c0, c1, c2, c3;
      c0.f = sc[g][ct][0]; c1.f = sc[g][ct][1]; c2.f = sc[g][ct][2]; c3.f = sc[g][ct][3];
      const unsigned pk0 = (c0.u >> 16) | (c1.u & 0xFFFF0000u);   // bf16 trunc pack
      const unsigned pk1 = (c2.u >> 16) | (c3.u & 0xFFFF0000u);
      *(uint2*)(PsW + (g * 16 + mi) * ROW + ct * 16 + quad * 4) = make_uint2(pk0, pk1);
    }
  bf16x8 pa0[2], pa1[2];
#pragma unroll
  for (int g = 0; g < 2; g++) {
    pa0[g] = *(const bf16x8*)(PsW + (g * 16 + mi) * ROW + quad * 8);
    pa1[g] = *(const bf16x8*)(PsW + (g * 16 + mi) * ROW + 32 + quad * 8);
  }
#pragma unroll
  for (int ct = 0; ct < 4; ct++) {
    const bf16x8 vf0 = *(const bf16x8*)(Vts + (ct * 16 + mi) * ROW + quad * 8);
    const bf16x8 vf1 = *(const bf16x8*)(Vts + (ct * 16 + mi) * ROW + 32 + quad * 8);
#pragma unroll
    for (int g = 0; g < 2; g++) {
      oc[g][ct] = __builtin_amdgcn_mfma_f32_16x16x32_bf16(pa0[g], vf0, oc[g][ct], 0, 0, 0);
      oc[g][ct] = __builtin_amdgcn_mfma_f32_16x16x32_bf16(pa1[g], vf1, oc[g][ct], 0, 0, 0);
    }
  }
}

// grid (T/128, B, NH), 256 thr = 4 waves x 32 q-rows (2 groups of 16)
__global__ __launch_bounds__(256, 4) void attn_mfma(const unsigned short* __restrict__ Qg,
                                                    const unsigned short* __restrict__ Kg,
                                                    const unsigned short* __restrict__ Vtg,
                                                    const int* __restrict__ nkeys,
                                                    unsigned short* __restrict__ av) {
  __shared__ alignas(16) unsigned short smem[18688];
  unsigned short* Ks  = smem;
  unsigned short* Vts = smem + 4608;
  unsigned short* Qs  = smem + 9216;
  float* Ls = (float*)(smem + 18432);

  const int tid  = threadIdx.x;
  const int lane = tid & 63;
  const int wv   = tid >> 6;
  const int mi   = lane & 15;
  const int quad = lane >> 4;
  const int i0 = blockIdx.x * 128;
  const int b  = blockIdx.y;
  const int n  = blockIdx.z;
  const size_t base = ((size_t)b * NHEAD + n) * T_LEN * DHEAD;
  const int nk = nkeys[b];

  for (int it = tid; it < 1024; it += 256) {
    const int r = it >> 3, c8 = (it & 7) * 8;
    *(uint4*)(Qs + r * ROW + c8) = *(const uint4*)(Qg + base + (size_t)(i0 + r) * DHEAD + c8);
  }
  __syncthreads();
  bf16x8 qb[2][2];
#pragma unroll
  for (int g = 0; g < 2; g++) {
    qb[g][0] = *(const bf16x8*)(Qs + (wv * 32 + g * 16 + mi) * ROW + quad * 8);
    qb[g][1] = *(const bf16x8*)(Qs + (wv * 32 + g * 16 + mi) * ROW + 32 + quad * 8);
  }

  f32x4 oc[2][4] = {};
  float rs[2] = {0.f, 0.f};
  unsigned short* PsW = Qs + wv * 2304;   // 32*ROW per wave (aliases Qs; safe after barrier)

  const int nmain = nk & ~63;
  for (int j0 = 0; j0 < nmain; j0 += 64) {
    for (int it = tid; it < 512; it += 256) {
      const int r = it >> 3, c8 = (it & 7) * 8;
      *(uint4*)(Ks  + r * ROW + c8) = *(const uint4*)(Kg  + base + (size_t)(j0 + r) * DHEAD + c8);
      *(uint4*)(Vts + r * ROW + c8) = *(const uint4*)(Vtg + base + (size_t)r * T_LEN + j0 + c8);
    }
    __syncthreads();
    attn_chunk<false>(j0, nk, mi, quad, Ks, Vts, PsW, qb, oc, rs);
    __syncthreads();
  }
  if (nmain < nk) {
    for (int it = tid; it < 512; it += 256) {
      const int r = it >> 3, c8 = (it & 7) * 8;
      *(uint4*)(Ks  + r * ROW + c8) = *(const uint4*)(Kg  + base + (size_t)(nmain + r) * DHEAD + c8);
      *(uint4*)(Vts + r * ROW + c8) = *(const uint4*)(Vtg + base + (size_t)r * T_LEN + nmain + c8);
    }
    __syncthreads();
    attn_chunk<true>(nmain, nk, mi, quad, Ks, Vts, PsW, qb, oc, rs);
  }

#pragma unroll
  for (int g = 0; g < 2; g++) {
    float t = rs[g];
    t += __shfl_xor(t, 16, 64);
    t += __shfl_xor(t, 32, 64);
    rs[g] = t;
  }
  if (quad == 0) { Ls[wv * 32 + mi] = rs[0]; Ls[wv * 32 + 16 + mi] = rs[1]; }
  __syncthreads();
  float linv[2][4];
#pragma unroll
  for (int g = 0; g < 2; g++)
#pragma unroll
    for (int r = 0; r < 4; r++) {
      const float l = Ls[wv * 32 + g * 16 + quad * 4 + r];
      linv[g][r] = (l > 0.f) ? (1.f / l) : 0.f;
    }
#pragma unroll
  for (int g = 0; g < 2; g++)
#pragma unroll
    for (int ct = 0; ct < 4; ct++)
#pragma unroll
      for (int r = 0; r < 4; r++) {
        const int q = i0 + wv * 32 + g * 16 + quad * 4 + r;
        const int d = ct * 16 + mi;
        av[((size_t)q * BSZ + b) * DMODEL + n * DHEAD + d] = f2bf(oc[g][ct][r] * linv[g][r]);
      }
}

// ---- out = LayerNorm(h + attn_out)*g + b  (ao bf16, float4 paths) ----
__global__ __launch_bounds__(256) void ln_kernel(const float* __restrict__ h,
                                                 const unsigned short* __restrict__ ao,
                                                 const float* __restrict__ g,
                                                 const float* __restrict__ bb,
                                                 float* __restrict__ out) {
  __shared__ float red[16];
  const int row = blockIdx.x;
  const int tid = threadIdx.x;
  const size_t base = (size_t)row * DMODEL;
  const int c = tid * 4;
  const float4 hv = *(const float4*)(h + base + c);
  const ushort4 a4 = *(const ushort4*)(ao + base + c);
  float x[4] = { hv.x + bf2f(a4.x), hv.y + bf2f(a4.y), hv.z + bf2f(a4.z), hv.w + bf2f(a4.w) };
  float s = 0.f, sq = 0.f;
#pragma unroll
  for (int k = 0; k < 4; k++) { s += x[k]; sq += x[k] * x[k]; }
#pragma unroll
  for (int off = 32; off; off >>= 1) { s += __shfl_xor(s, off, 64); sq += __shfl_xor(sq, off, 64); }
  const int wv = tid >> 6, lane = tid & 63;
  if (lane == 0) { red[wv] = s; red[8 + wv] = sq; }
  __syncthreads();
  if (tid == 0) {
    float ts = 0.f, tq = 0.f;
    for (int w = 0; w < 4; w++) { ts += red[w]; tq += red[8 + w]; }
    red[4] = ts; red[12] = tq;
  }
  __syncthreads();
  const float mu  = red[4] * (1.f / DMODEL);
  const float var = red[12] * (1.f / DMODEL) - mu * mu;
  const float inv = rsqrtf(var + 1e-5f);
  const float4 gv = *(const float4*)(g + c);
  const float4 bv = *(const float4*)(bb + c);
  float4 o;
  o.x = (x[0] - mu) * inv * gv.x + bv.x;
  o.y = (x[1] - mu) * inv * gv.y + bv.y;
  o.z = (x[2] - mu) * inv * gv.z + bv.z;
  o.w = (x[3] - mu) * inv * gv.w + bv.w;
  *(float4*)(out + base + c) = o;
}

extern "C" void kernel_launch(void* const* d_in, const int* in_sizes, int n_in,
                              void* d_out, int out_size, void* d_ws, size_t ws_size,
                              hipStream_t stream) {
  (void)in_sizes; (void)n_in; (void)out_size; (void)ws_size;
  const float* h           = (const float*)d_in[0];
  const unsigned char* msk = (const unsigned char*)d_in[1];
  const float* wq          = (const float*)d_in[2];
  const float* wkv         = (const float*)d_in[3];
  const float* wo          = (const float*)d_in[4];
  const float* lng         = (const float*)d_in[5];
  const float* lnb         = (const float*)d_in[6];
  float* out = (float*)d_out;

  const size_t E  = (size_t)T_LEN * BSZ * DMODEL;        // 8.39M
  const size_t WQ = (size_t)NHEAD * DHEAD * DMODEL;      // 1.05M
  char* ws = (char*)d_ws;
  int* nkeys            = (int*)ws;                       ws += 16;
  int* pos              = (int*)ws;                       ws += (size_t)BSZ * T_LEN * 4;
  unsigned short* h_bf  = (unsigned short*)ws;            ws += E * 2;
  unsigned short* wq_bf = (unsigned short*)ws;            ws += WQ * 2;
  unsigned short* wkv_bf= (unsigned short*)ws;            ws += 2 * WQ * 2;
  unsigned short* wo_bf = (unsigned short*)ws;            ws += WQ * 2;
  unsigned short* Qb    = (unsigned short*)ws;            ws += E * 2;
  unsigned short* Kb    = (unsigned short*)ws;            ws += E * 2;
  unsigned short* Vtb   = (unsigned short*)ws;            ws += E * 2;
  unsigned short* AV    = (unsigned short*)ws;            ws += E * 2;
  unsigned short* AO    = (unsigned short*)ws;

  const dim3 blk(256);
  cvt_prep<<<dim3(12289), blk, 0, stream>>>(h, wq, wkv, wo, msk,
                                            h_bf, wq_bf, wkv_bf, wo_bf, pos, nkeys);
  gemm_qkv<<<dim3(3 * DMODEL / 128, T_LEN * BSZ / 128), blk, 0, stream>>>(
      h_bf, wq_bf, wkv_bf, pos, Qb, Kb, Vtb);
  attn_mfma<<<dim3(T_LEN / 128, BSZ, NHEAD), blk, 0, stream>>>(Qb, Kb, Vtb, nkeys, AV);
  gemm_out<<<dim3(DMODEL / 128, T_LEN * BSZ / 128), blk, 0, stream>>>(AV, wo_bf, AO);
  ln_kernel<<<dim3(T_LEN * BSZ), blk, 0, stream>>>(h, AO, lng, lnb, out);
}